// Round 2
// baseline (153.903 us; speedup 1.0000x reference)
//
#include <hip/hip_runtime.h>

#define NA 8
#define NV 16
#define NS (NA * NV)          // 128 segments
#define NW 4                  // waves per block (256 threads)
#define FIX_SHIFT 43
#define FIX_MASK ((1ULL << FIX_SHIFT) - 1)
#define FIX_SCALE 2147483648.0f   // 2^31

// ---------------------------------------------------------------------------
// K1 v3: transposed cooperative loads.
// A wave processes a chunk of 32 rows = 1KB of preds + 1KB of attrs.
// Lane i loads the i-th contiguous 16B of each region -> every load
// instruction is 16 fully-used 64B segments (was 64 quarter-used segments).
// Lane 2r   holds row r preds[0:4] / attrs[0:4]
// Lane 2r+1 holds row r preds[4:8] / attrs[4:8]
// __shfl_xor(hs,1) (quad-perm DPP) gives both lanes the full row sigmoid sum;
// even lane does LDS atomics for attrs 0-3, odd lane for attrs 4-7.
// packed = (count=1) << 43 | round(per_node * 2^31); per-wave histogram
// replication; per-wave bound: <= 8 chunks * 32 rows = 256 rows -> sum < 2^39.
// 1-deep software pipeline: prefetch chunk c+stride while processing c.
// Epilogue: merged partials stored transposed [segment][block]; NO global
// atomics anywhere.
// ---------------------------------------------------------------------------

__device__ __forceinline__ float sig(float x) {
    return __builtin_amdgcn_rcpf(1.0f + __expf(-x));
}

__device__ __forceinline__ void process_chunk(
    float4 p, int4 a, int lane, unsigned long long* __restrict__ hw)
{
    float hs = sig(p.x) + sig(p.y) + sig(p.z) + sig(p.w);
    float s  = hs + __shfl_xor(hs, 1, 64);     // full row sum in both lanes
    float per_node = s * 0.125f;               // in (0,1]
    unsigned int fixed = (unsigned int)(per_node * FIX_SCALE);  // <= 2^31
    unsigned long long add = (1ULL << FIX_SHIFT) | (unsigned long long)fixed;
    const int abase = (lane & 1) << 2;         // even lane: attrs 0-3, odd: 4-7
    atomicAdd(&hw[((abase + 0) << 4) + a.x], add);
    atomicAdd(&hw[((abase + 1) << 4) + a.y], add);
    atomicAdd(&hw[((abase + 2) << 4) + a.z], add);
    atomicAdd(&hw[((abase + 3) << 4) + a.w], add);
}

__global__ __launch_bounds__(256) void k1_accum(
    const float* __restrict__ preds,           // [B, 8]
    const int*   __restrict__ attrs,           // [B, 8]
    unsigned long long* __restrict__ partials, // [NS, nb]
    int B, int nb)
{
    __shared__ unsigned long long h[NW][NS];
    for (int i = threadIdx.x; i < NW * NS; i += 256)
        ((unsigned long long*)h)[i] = 0ULL;
    __syncthreads();

    const int lane = threadIdx.x & 63;
    const int wave = threadIdx.x >> 6;
    unsigned long long* __restrict__ hw = h[wave];

    const float4* __restrict__ p4 = (const float4*)preds;
    const int4*   __restrict__ a4 = (const int4*)attrs;

    const int gw      = blockIdx.x * NW + wave;  // global wave id
    const int nwv     = nb * NW;                 // total waves
    const int nchunks = B >> 5;                  // 32 rows per chunk

    int c = gw;
    if (c < nchunks) {
        // prologue load (chunk c): lane's 16B slice, fully coalesced
        float4 p = p4[(size_t)c * 64 + lane];
        int4   a = a4[(size_t)c * 64 + lane];
        for (;;) {
            const int  cn   = c + nwv;
            const bool more = (cn < nchunks);    // wave-uniform
            float4 pn; int4 an;
            if (more) {                          // prefetch next chunk
                pn = p4[(size_t)cn * 64 + lane];
                an = a4[(size_t)cn * 64 + lane];
            }
            process_chunk(p, a, lane, hw);
            if (!more) break;
            p = pn; a = an; c = cn;
        }
    }

    // tail: B % 32 leftover rows, handled by wave 0 of block 0
    const int rem = B & 31;
    if (rem && blockIdx.x == 0 && wave == 0 && lane < rem * 2) {
        const size_t base = (size_t)(B >> 5) * 64;
        float4 p = p4[base + lane];
        int4   a = a4[base + lane];
        process_chunk(p, a, lane, hw);           // pairs fully active
    }
    __syncthreads();

    // merge 4 per-wave copies; packed fields can't overflow
    // (block handles <= 1024 rows -> sum < 2^41, count < 2^21)
    if (threadIdx.x < NS) {
        unsigned long long m = h[0][threadIdx.x] + h[1][threadIdx.x]
                             + h[2][threadIdx.x] + h[3][threadIdx.x];
        partials[(size_t)threadIdx.x * nb + blockIdx.x] = m;
    }
}

// ---------------------------------------------------------------------------
// K2: one block per segment. Coalesced read of nb packed partials, unpack,
// u64/u32 accumulate, wave+LDS reduce, fp64 mean.
// ---------------------------------------------------------------------------
__global__ __launch_bounds__(256) void k2_reduce(
    const unsigned long long* __restrict__ partials, // [NS, nb]
    double* __restrict__ means,                      // [NS]
    int*    __restrict__ pres,                       // [NS]
    int nb)
{
    const int s = blockIdx.x;
    unsigned long long sum = 0ULL;
    unsigned int cnt = 0u;
    for (int b = threadIdx.x; b < nb; b += 256) {
        unsigned long long p = partials[(size_t)s * nb + b];
        cnt += (unsigned int)(p >> FIX_SHIFT);
        sum += (p & FIX_MASK);
    }
    for (int off = 32; off > 0; off >>= 1) {
        sum += __shfl_down(sum, off, 64);
        cnt += __shfl_down(cnt, off, 64);
    }
    __shared__ unsigned long long ws_[4];
    __shared__ unsigned int wc_[4];
    const int wave = threadIdx.x >> 6;
    if ((threadIdx.x & 63) == 0) { ws_[wave] = sum; wc_[wave] = cnt; }
    __syncthreads();
    if (threadIdx.x == 0) {
        unsigned long long S = ws_[0] + ws_[1] + ws_[2] + ws_[3];
        unsigned int C = wc_[0] + wc_[1] + wc_[2] + wc_[3];
        means[s] = C ? ((double)S * (1.0 / (double)FIX_SCALE)) / (double)C : 0.0;
        pres[s]  = C ? 1 : 0;
    }
}

// ---------------------------------------------------------------------------
// K3: 1 block, 128 threads. Pairwise squared diffs of means within each
// attribute (i<j, both present), fp64 reduce, scalar out.
// ---------------------------------------------------------------------------
__global__ __launch_bounds__(128) void k3_finalize(
    const double* __restrict__ means,
    const int*    __restrict__ pres,
    float* __restrict__ out)
{
    __shared__ double s_mean[NS];
    __shared__ int    s_pres[NS];
    const int t = threadIdx.x;
    s_mean[t] = means[t];
    s_pres[t] = pres[t];
    __syncthreads();

    const int a = t >> 4;
    const int i = t & (NV - 1);
    double loss = 0.0;
    int    ncmp = 0;
    if (s_pres[t]) {
        const double mi = s_mean[t];
        for (int j = i + 1; j < NV; ++j) {
            const int sj = a * NV + j;
            if (s_pres[sj]) {
                const double d = mi - s_mean[sj];
                loss += d * d;
                ncmp += 1;
            }
        }
    }
    for (int off = 32; off > 0; off >>= 1) {
        loss += __shfl_down(loss, off, 64);
        ncmp += __shfl_down(ncmp, off, 64);
    }
    __shared__ double w_loss[2];
    __shared__ int    w_ncmp[2];
    const int wave = t >> 6;
    if ((t & 63) == 0) { w_loss[wave] = loss; w_ncmp[wave] = ncmp; }
    __syncthreads();
    if (t == 0) {
        const double total = w_loss[0] + w_loss[1];
        const int    n     = w_ncmp[0] + w_ncmp[1];
        out[0] = (n > 0) ? (float)(total / (double)n) : 0.0f;
    }
}

extern "C" void kernel_launch(void* const* d_in, const int* in_sizes, int n_in,
                              void* d_out, int out_size, void* d_ws, size_t ws_size,
                              hipStream_t stream) {
    const float* preds = (const float*)d_in[0];
    const int*   attrs = (const int*)d_in[1];
    float*       out   = (float*)d_out;

    const int B = in_sizes[1] / NA;

    // nb=2048: 8 blocks/CU. Tail of workspace: means (128 f64) + pres (128 i32).
    const size_t tail = NS * sizeof(double) + NS * sizeof(int);
    int nb = 2048;
    while (nb > 512 &&
           ws_size < (size_t)NS * nb * sizeof(unsigned long long) + tail) {
        nb >>= 1;
    }

    unsigned long long* partials = (unsigned long long*)d_ws;
    double* means = (double*)((char*)d_ws + (size_t)NS * nb * sizeof(unsigned long long));
    int*    pres  = (int*)(means + NS);

    k1_accum<<<nb, 256, 0, stream>>>(preds, attrs, partials, B, nb);
    k2_reduce<<<NS, 256, 0, stream>>>(partials, means, pres, nb);
    k3_finalize<<<1, 128, 0, stream>>>(means, pres, out);
}